// Round 6
// baseline (5454.177 us; speedup 1.0000x reference)
//
#include <hip/hip_runtime.h>

#define NBATCH 64
#define NSEQ   32
#define NI     31
#define NC     16
#define NH     128
#define NW     256
#define NOUT   10
#define NSUB   62          // 31 intervals * 2 substeps

#define NGRP 8             // batch groups
#define GB   8             // batch rows per group
#define NSL  32            // slice blocks per group
#define NBLK (NGRP*NSL)    // 256 blocks = 1 per CU (LDS-forced)
#define BS   512

// per-slice weight ownership
#define L1R 8              // fw0 rows  (256/32)
#define L2R 8              // fw1 rows  (256/32)
#define L3H 4              // h-dims of fw2 (128/32)
#define L3R 64             // fw2 rows = L3H*16

// padded LDS strides (floats)
#define P128 132
#define P256 260

// workspace layout (bytes) — all tagged-u64 buffers
#define WS_H1    0                          // [64][256] u64 = 128 KB
#define WS_H2    (128*1024)                 // [64][256] u64 = 128 KB
#define WS_KV    (256*1024)                 // [6][64][128] u64 = 384 KB
#define WS_TOTAL_U64 (2*64*256 + 6*64*128)  // 81920

__device__ const float ATAB[6][5] = {
  {0.f, 0.f, 0.f, 0.f, 0.f},
  {0.161f, 0.f, 0.f, 0.f, 0.f},
  {-0.008480655492356989f, 0.335480655492357f, 0.f, 0.f, 0.f},
  {2.8971530571054935f, -6.359448489975075f, 4.3622954328695815f, 0.f, 0.f},
  {5.325864828439257f, -11.748883564062828f, 7.4955393428898365f, -0.09249506636175525f, 0.f},
  {5.86145544294642f, -12.92096931784711f, 8.159367898576159f, -0.071584973281401f, -0.028269050394068383f}
};
__device__ const float CNODE[6] = {0.f, 0.161f, 0.327f, 0.9f, 0.9800255409045097f, 1.f};
__device__ const float BTAB[6]  = {0.09646076681806523f, 0.01f, 0.4798896504144996f,
                                   1.379008574103742f, -3.290069515436081f, 2.324710524099774f};

__device__ __forceinline__ float softplusf_(float x) {
  return fmaxf(x, 0.0f) + log1pf(expf(-fabsf(x)));
}
__device__ __forceinline__ float dot4(float4 a, float4 b) {
  return (a.x*b.x + a.y*b.y) + (a.z*b.z + a.w*b.w);
}

// device-coherent 8B transport (sc0 sc1: bypass L1+L2, coherent at IF)
typedef unsigned long long u64;
__device__ __forceinline__ u64 gload64(const u64* p) {
  return __hip_atomic_load(p, __ATOMIC_RELAXED, __HIP_MEMORY_SCOPE_AGENT);
}
__device__ __forceinline__ void gstore64(u64* p, u64 v) {
  __hip_atomic_store(p, v, __ATOMIC_RELAXED, __HIP_MEMORY_SCOPE_AGENT);
}
__device__ __forceinline__ u64 packvt(float v, unsigned tag) {
  return ((u64)tag << 32) | (u64)__float_as_uint(v);
}

__global__ void tag_init(u64* ws) {
  const int idx = blockIdx.x * blockDim.x + threadIdx.x;   // 64*256 = 16384 threads
  #pragma unroll
  for (int i = 0; i < 5; ++i) {
    const int e = idx + 16384*i;
    if (e < WS_TOTAL_U64) gstore64(&ws[e], 0ull);
  }
}

__global__ __launch_bounds__(BS) void ncde_fwd(
    const float* __restrict__ ts,
    const float* __restrict__ cd, const float* __restrict__ cc,
    const float* __restrict__ cb, const float* __restrict__ ca,
    const float* __restrict__ iw0, const float* __restrict__ ib0,
    const float* __restrict__ iw1, const float* __restrict__ ib1,
    const float* __restrict__ iw2, const float* __restrict__ ib2,
    const float* __restrict__ fw0, const float* __restrict__ fb0,
    const float* __restrict__ fw1, const float* __restrict__ fb1,
    const float* __restrict__ fw2, const float* __restrict__ fb2,
    const float* __restrict__ lw,  const float* __restrict__ lb,
    u64* __restrict__ h1g, u64* __restrict__ h2g,
    u64* __restrict__ kvg, float* __restrict__ out)
{
  const int t   = threadIdx.x;
  const int g   = blockIdx.x & 7;         // group (same-XCD heuristic; correctness-independent)
  const int s   = blockIdx.x >> 3;        // slice 0..31
  const int gr0 = g * GB;

  __shared__ float fw0s[L1R][P128];
  __shared__ float fw1s[L2R][P256];
  __shared__ float fw2s[L3R][P256];
  __shared__ float h1s[GB][P256];
  __shared__ float h2s[GB][P256];
  __shared__ float ysv[GB][P128];
  __shared__ float yloc[GB][NH];
  __shared__ float dxs[GB][NC];
  __shared__ float x0s[GB][NC];
  __shared__ float fb0s[L1R], fb1s[L2R], fb2s[L3R];
  __shared__ float tss[NSEQ];
  __shared__ float lgs[GB][NOUT], lses[GB];

  // ---- one-time: this slice's weights -> LDS ----
  {
    if (t < 256) {                       // fw0: 8 rows x 32 f4
      int row = t >> 5, j = t & 31;
      *(float4*)&fw0s[row][4*j] = *(const float4*)&fw0[(size_t)(s*L1R + row)*NH + 4*j];
    }
    {                                    // fw1: 8 rows x 64 f4 -> 1 f4/thread
      int r2 = t >> 6, j2 = t & 63;
      *(float4*)&fw1s[r2][4*j2] = *(const float4*)&fw1[(size_t)(s*L2R + r2)*NW + 4*j2];
    }
    #pragma unroll
    for (int i = 0; i < 8; ++i) {        // fw2: 64 rows x 64 f4 -> 8 f4/thread
      int e = t + BS*i; int r2 = e >> 6, j2 = e & 63;
      *(float4*)&fw2s[r2][4*j2] = *(const float4*)&fw2[(size_t)(s*L3R + r2)*NW + 4*j2];
    }
    if (t < L1R) fb0s[t] = fb0[s*L1R + t];
    if (t < L2R) fb1s[t] = fb1[s*L2R + t];
    if (t < L3R) fb2s[t] = fb2[s*L3R + t];
    if (t < NSEQ) tss[t] = ts[t];
  }

  // ---- init MLP (redundant per block, fully local) ----
  if (t < GB*NC) { int r = t >> 4, c = t & 15; x0s[r][c] = ca[((size_t)(gr0 + r)*NI)*NC + c]; }
  __syncthreads();
  #pragma unroll
  for (int i = 0; i < 4; ++i) {          // h1i: 2048 outs
    int e = t + BS*i; int r = e >> 8, row = e & 255;
    float a = ib0[row];
    #pragma unroll
    for (int k = 0; k < NC; ++k) a += iw0[row*NC + k] * x0s[r][k];
    h1s[r][row] = fmaxf(a, 0.f);
  }
  __syncthreads();
  #pragma unroll
  for (int i = 0; i < 4; ++i) {          // h2i
    int e = t + BS*i; int r = e >> 8, row = e & 255;
    float a = ib1[row];
    const float4* wr = (const float4*)&iw1[(size_t)row*NW];
    for (int k = 0; k < 64; ++k) a += dot4(wr[k], *(const float4*)&h1s[r][4*k]);
    h2s[r][row] = fmaxf(a, 0.f);
  }
  __syncthreads();
  #pragma unroll
  for (int i = 0; i < 2; ++i) {          // y0: 1024 outs
    int e = t + BS*i; int r = e >> 7, row = e & 127;
    float a = ib2[row];
    const float4* wr = (const float4*)&iw2[(size_t)row*NW];
    for (int k = 0; k < 64; ++k) a += dot4(wr[k], *(const float4*)&h2s[r][4*k]);
    yloc[r][row] = a;
  }
  __syncthreads();

  // ---- thread mappings ----
  const int yr  = t >> 5, yc4 = 4*(t & 31);     // t<256: one y-f4 (batch yr, cols yc4..+3)
  const int o   = t >> 3, q8 = t & 7;           // L1/L2: 8 threads per output
  const int orow = o & 7, obat = o >> 3;
  const int l3row = t & 63, l3h = l3row >> 4, l3c = l3row & 15, l3b = t >> 6;

  // ---- y and k stages live in registers (t<256) ----
  float4 yreg, kreg[6];
  if (t < 256) yreg = *(const float4*)&yloc[yr][yc4];

  unsigned p = 0;   // global phase counter (identical sequence on every block)

  // ---- 62 Tsit5 substeps ----
  for (int ss = 0; ss < NSUB; ++ss) {
    const int iv = ss >> 1, jv = ss & 1;
    const float h = (tss[iv+1] - tss[iv]) * 0.5f;
    const float t0f = (float)jv * h;

    float cdv = 0.f, ccv = 0.f, cbv = 0.f;
    if (t >= 256 && t < 256 + GB*NC) {
      const int tc = t - 256;
      const size_t base = ((size_t)(gr0 + (tc >> 4))*NI + iv)*NC + (tc & 15);
      cdv = cd[base]; ccv = cc[base]; cbv = cb[base];
    }

    for (int st = 0; st < 6; ++st) {
      const unsigned ph1 = p + 1, ph2 = p + 2, phk = p + 3;
      p += 3;

      // ---- phase A: stage state from registers + dX/dt ----
      if (t < 256) {
        float4 v = yreg;
        for (int jj = 0; jj < st; ++jj) {
          const float a = h * ATAB[st][jj];
          v.x += a*kreg[jj].x; v.y += a*kreg[jj].y;
          v.z += a*kreg[jj].z; v.w += a*kreg[jj].w;
        }
        *(float4*)&ysv[yr][yc4] = v;
      } else if (t < 256 + GB*NC) {
        const int tc = t - 256;
        const float f = t0f + CNODE[st] * h;
        dxs[tc >> 4][tc & 15] = (3.f*cdv*f + 2.f*ccv)*f + cbv;
      }
      __syncthreads();

      // ---- L1: h1 slice (8 rows x 8 batch, 8 thr/out) -> tagged store ----
      {
        float a0 = 0.f, a1 = 0.f;
        #pragma unroll
        for (int i = 0; i < 4; i += 2) {
          a0 += dot4(*(const float4*)&fw0s[orow][4*(q8+8*i)],     *(const float4*)&ysv[obat][4*(q8+8*i)]);
          a1 += dot4(*(const float4*)&fw0s[orow][4*(q8+8*(i+1))], *(const float4*)&ysv[obat][4*(q8+8*(i+1))]);
        }
        float a = a0 + a1;
        a += __shfl_xor(a, 1); a += __shfl_xor(a, 2); a += __shfl_xor(a, 4);
        if (q8 == 0)
          gstore64(&h1g[(gr0 + obat)*NW + s*L1R + orow], packvt(softplusf_(fb0s[orow] + a), ph1));
      }

      // ---- consume h1: poll tagged entries, stage into LDS ----
      {
        const u64* basep = h1g + (size_t)gr0 * NW;
        u64 vv[4];
        for (;;) {
          bool ok = true;
          #pragma unroll
          for (int i = 0; i < 4; ++i) {
            vv[i] = gload64(basep + t + BS*i);
            ok &= ((unsigned)(vv[i] >> 32) == ph1);
          }
          if (ok) break;
          __builtin_amdgcn_s_sleep(1);
        }
        #pragma unroll
        for (int i = 0; i < 4; ++i) {
          const int e = t + BS*i;
          h1s[e >> 8][e & 255] = __uint_as_float((unsigned)vv[i]);
        }
      }
      __syncthreads();

      // ---- L2: h2 slice -> tagged store ----
      {
        float a0 = 0.f, a1 = 0.f;
        #pragma unroll
        for (int i = 0; i < 8; i += 2) {
          a0 += dot4(*(const float4*)&fw1s[orow][4*(q8+8*i)],     *(const float4*)&h1s[obat][4*(q8+8*i)]);
          a1 += dot4(*(const float4*)&fw1s[orow][4*(q8+8*(i+1))], *(const float4*)&h1s[obat][4*(q8+8*(i+1))]);
        }
        float a = a0 + a1;
        a += __shfl_xor(a, 1); a += __shfl_xor(a, 2); a += __shfl_xor(a, 4);
        if (q8 == 0)
          gstore64(&h2g[(gr0 + obat)*NW + s*L2R + orow], packvt(softplusf_(fb1s[orow] + a), ph2));
      }

      // ---- consume h2 ----
      {
        const u64* basep = h2g + (size_t)gr0 * NW;
        u64 vv[4];
        for (;;) {
          bool ok = true;
          #pragma unroll
          for (int i = 0; i < 4; ++i) {
            vv[i] = gload64(basep + t + BS*i);
            ok &= ((unsigned)(vv[i] >> 32) == ph2);
          }
          if (ok) break;
          __builtin_amdgcn_s_sleep(1);
        }
        #pragma unroll
        for (int i = 0; i < 4; ++i) {
          const int e = t + BS*i;
          h2s[e >> 8][e & 255] = __uint_as_float((unsigned)vv[i]);
        }
      }
      __syncthreads();

      // ---- L3: one fw2 row per thread, 4 accumulators, 16-lane reduce -> tagged store ----
      {
        const float4* wr = (const float4*)&fw2s[l3row][0];
        const float4* xr = (const float4*)&h2s[l3b][0];
        float a0 = 0.f, a1 = 0.f, a2 = 0.f, a3 = 0.f;
        #pragma unroll 4
        for (int i = 0; i < 64; i += 4) {
          a0 += dot4(wr[i+0], xr[i+0]);
          a1 += dot4(wr[i+1], xr[i+1]);
          a2 += dot4(wr[i+2], xr[i+2]);
          a3 += dot4(wr[i+3], xr[i+3]);
        }
        float v0 = tanhf(((a0+a1)+(a2+a3)) + fb2s[l3row]) * dxs[l3b][l3c];
        v0 += __shfl_xor(v0, 1);
        v0 += __shfl_xor(v0, 2);
        v0 += __shfl_xor(v0, 4);
        v0 += __shfl_xor(v0, 8);
        if (l3c == 0)
          gstore64(&kvg[((size_t)st*NBATCH + gr0 + l3b)*NH + s*L3H + l3h], packvt(v0, phk));
      }

      // ---- consume k-stage into registers (one f4 per t<256 thread) ----
      if (t < 256) {
        const u64* kp = &kvg[((size_t)st*NBATCH + gr0 + yr)*NH + yc4];
        u64 vv[4];
        for (;;) {
          bool ok = true;
          #pragma unroll
          for (int i = 0; i < 4; ++i) {
            vv[i] = gload64(kp + i);
            ok &= ((unsigned)(vv[i] >> 32) == phk);
          }
          if (ok) break;
          __builtin_amdgcn_s_sleep(1);
        }
        kreg[st].x = __uint_as_float((unsigned)vv[0]);
        kreg[st].y = __uint_as_float((unsigned)vv[1]);
        kreg[st].z = __uint_as_float((unsigned)vv[2]);
        kreg[st].w = __uint_as_float((unsigned)vv[3]);
      }
    }

    // ---- y update in registers ----
    if (t < 256) {
      #pragma unroll
      for (int s2 = 0; s2 < 6; ++s2) {
        const float a = h * BTAB[s2];
        yreg.x += a*kreg[s2].x; yreg.y += a*kreg[s2].y;
        yreg.z += a*kreg[s2].z; yreg.w += a*kreg[s2].w;
      }
    }
  }

  // ---- write y back for readout ----
  if (t < 256) *(float4*)&yloc[yr][yc4] = yreg;
  __syncthreads();

  // ---- readout by slice 0 of each group ----
  if (s == 0) {
    if (t < GB*NOUT) {
      const int r = t / NOUT, oo = t % NOUT;
      float a = lb[oo];
      const float4* wr = (const float4*)&lw[(size_t)oo*NH];
      #pragma unroll
      for (int k = 0; k < 32; ++k) a += dot4(wr[k], *(const float4*)&yloc[r][4*k]);
      lgs[r][oo] = a;
    }
    __syncthreads();
    if (t < GB) {
      float m = lgs[t][0];
      for (int oo = 1; oo < NOUT; ++oo) m = fmaxf(m, lgs[t][oo]);
      float se = 0.f;
      for (int oo = 0; oo < NOUT; ++oo) se += expf(lgs[t][oo] - m);
      lses[t] = m + logf(se);
    }
    __syncthreads();
    if (t < GB*NOUT) {
      const int r = t / NOUT, oo = t % NOUT;
      out[(gr0 + r)*NOUT + oo] = lgs[r][oo] - lses[r];
    }
  }
}

extern "C" void kernel_launch(void* const* d_in, const int* in_sizes, int n_in,
                              void* d_out, int out_size, void* d_ws, size_t ws_size,
                              hipStream_t stream) {
  const float* ts  = (const float*)d_in[0];
  const float* cd  = (const float*)d_in[1];
  const float* cc  = (const float*)d_in[2];
  const float* cb  = (const float*)d_in[3];
  const float* ca  = (const float*)d_in[4];
  const float* iw0 = (const float*)d_in[5];
  const float* ib0 = (const float*)d_in[6];
  const float* iw1 = (const float*)d_in[7];
  const float* ib1 = (const float*)d_in[8];
  const float* iw2 = (const float*)d_in[9];
  const float* ib2 = (const float*)d_in[10];
  const float* fw0 = (const float*)d_in[11];
  const float* fb0 = (const float*)d_in[12];
  const float* fw1 = (const float*)d_in[13];
  const float* fb1 = (const float*)d_in[14];
  const float* fw2 = (const float*)d_in[15];
  const float* fb2 = (const float*)d_in[16];
  const float* lw  = (const float*)d_in[17];
  const float* lb  = (const float*)d_in[18];

  char* ws = (char*)d_ws;
  u64* h1g = (u64*)(ws + WS_H1);
  u64* h2g = (u64*)(ws + WS_H2);
  u64* kvg = (u64*)(ws + WS_KV);

  tag_init<<<64, 256, 0, stream>>>((u64*)ws);
  ncde_fwd<<<NBLK, BS, 0, stream>>>(ts, cd, cc, cb, ca, iw0, ib0, iw1, ib1, iw2, ib2,
                                    fw0, fb0, fw1, fb1, fw2, fb2, lw, lb,
                                    h1g, h2g, kvg, (float*)d_out);
}

// Round 9
// 4265.891 us; speedup vs baseline: 1.2786x; 1.2786x over previous
//
#include <hip/hip_runtime.h>

#define NBATCH 64
#define NSEQ   32
#define NI     31
#define NC     16
#define NH     128
#define NW     256
#define NOUT   10
#define NSUB   62          // 31 intervals * 2 substeps

#define NGRP 8             // batch groups
#define GB   8             // batch rows per group
#define NSL  32            // slice blocks per group
#define NBLK (NGRP*NSL)    // 256 blocks = 1 per CU (LDS-forced)
#define BS   512

// per-slice weight ownership
#define L1R 8              // fw0 rows  (256/32)
#define L2R 8              // fw1 rows  (256/32)
#define L3H 4              // h-dims of fw2 (128/32)
#define L3R 64             // fw2 rows = L3H*16

// padded LDS strides (floats)
#define P128 132
#define P256 260

// workspace layout (bytes)
#define WS_BAR   0                       // 8 groups * 32 slots * 64B = 16 KB
#define WS_H1    16384                   // [8grp][32sl][8b][8r] f32 = 64 KB
#define WS_H2    (16384 + 65536)         // same = 64 KB
#define WS_KV    (16384 + 131072)        // [8grp][6st][32sl][8b][4] f32 = 192 KB

typedef float f4v __attribute__((ext_vector_type(4)));

__device__ const float ATAB[6][5] = {
  {0.f, 0.f, 0.f, 0.f, 0.f},
  {0.161f, 0.f, 0.f, 0.f, 0.f},
  {-0.008480655492356989f, 0.335480655492357f, 0.f, 0.f, 0.f},
  {2.8971530571054935f, -6.359448489975075f, 4.3622954328695815f, 0.f, 0.f},
  {5.325864828439257f, -11.748883564062828f, 7.4955393428898365f, -0.09249506636175525f, 0.f},
  {5.86145544294642f, -12.92096931784711f, 8.159367898576159f, -0.071584973281401f, -0.028269050394068383f}
};
__device__ const float CNODE[6] = {0.f, 0.161f, 0.327f, 0.9f, 0.9800255409045097f, 1.f};
__device__ const float BTAB[6]  = {0.09646076681806523f, 0.01f, 0.4798896504144996f,
                                   1.379008574103742f, -3.290069515436081f, 2.324710524099774f};

__device__ __forceinline__ float softplusf_(float x) {
  return fmaxf(x, 0.0f) + log1pf(expf(-fabsf(x)));
}
__device__ __forceinline__ float dot4(float4 a, float4 b) {
  return (a.x*b.x + a.y*b.y) + (a.z*b.z + a.w*b.w);
}

// ---- device-coherent transport (agent scope; proven path from R3-R5) ----
__device__ __forceinline__ void sta_f32(float* p, float v) {
  __hip_atomic_store(p, v, __ATOMIC_RELAXED, __HIP_MEMORY_SCOPE_AGENT);
}
// wider variants: same scope bits the compiler emits for agent atomics (sc0 sc1
// = bypass L1+L2, served at the IF coherence point), just 16B at a time.
// ext_vector_type binds to the "v" constraint as a native <4 x float>.
__device__ __forceinline__ void sta_f32x4(float* p, f4v v) {
  asm volatile("global_store_dwordx4 %0, %1, off sc0 sc1" :: "v"(p), "v"(v) : "memory");
}
__device__ __forceinline__ f4v lda_f32x4(const float* p) {
  f4v r;
  asm volatile("global_load_dwordx4 %0, %1, off sc0 sc1\n\ts_waitcnt vmcnt(0)"
               : "=v"(r) : "v"(p) : "memory");
  return r;
}

// group barrier (R4-proven): per-block slots + one-wave ballot poll.
// Explicit vmcnt drain first: inline-asm data stores aren't compiler-tracked.
#define SLOT_STRIDE 16     // 16 u32 = 64B per slot
__device__ __forceinline__ void group_barrier(unsigned* slots, int myslot, unsigned seq) {
  asm volatile("s_waitcnt vmcnt(0)" ::: "memory");
  __syncthreads();
  if (threadIdx.x == 0) {
    __hip_atomic_store(&slots[myslot * SLOT_STRIDE], seq,
                       __ATOMIC_RELAXED, __HIP_MEMORY_SCOPE_AGENT);
  }
  if (threadIdx.x < 64) {
    const int lane = threadIdx.x & 31;
    for (;;) {
      const unsigned v = __hip_atomic_load(&slots[lane * SLOT_STRIDE],
                                           __ATOMIC_RELAXED, __HIP_MEMORY_SCOPE_AGENT);
      if (__all(v >= seq)) break;
      __builtin_amdgcn_s_sleep(1);
    }
  }
  __syncthreads();
}

__global__ void bar_init(unsigned* bar) {
  const int n = NGRP * NSL * SLOT_STRIDE;   // 4096
  for (int i = threadIdx.x; i < n; i += blockDim.x)
    __hip_atomic_store(&bar[i], 0u, __ATOMIC_RELAXED, __HIP_MEMORY_SCOPE_AGENT);
}

__global__ __launch_bounds__(BS) void ncde_fwd(
    const float* __restrict__ ts,
    const float* __restrict__ cd, const float* __restrict__ cc,
    const float* __restrict__ cb, const float* __restrict__ ca,
    const float* __restrict__ iw0, const float* __restrict__ ib0,
    const float* __restrict__ iw1, const float* __restrict__ ib1,
    const float* __restrict__ iw2, const float* __restrict__ ib2,
    const float* __restrict__ fw0, const float* __restrict__ fb0,
    const float* __restrict__ fw1, const float* __restrict__ fb1,
    const float* __restrict__ fw2, const float* __restrict__ fb2,
    const float* __restrict__ lw,  const float* __restrict__ lb,
    unsigned* __restrict__ bar, float* __restrict__ h1c, float* __restrict__ h2c,
    float* __restrict__ kvc, float* __restrict__ out)
{
  const int t   = threadIdx.x;
  const int g   = blockIdx.x & 7;         // group (XCD heuristic; correctness-independent)
  const int s   = blockIdx.x >> 3;        // slice 0..31
  const int gr0 = g * GB;
  unsigned* slots = bar + g * NSL * SLOT_STRIDE;
  unsigned  bseq  = 0;
  float* h1cg = h1c + g * (NSL*GB*L1R);   // [32][8][8]
  float* h2cg = h2c + g * (NSL*GB*L2R);
  float* kvcg = kvc + g * (6*NSL*GB*4);   // [6][32][8][4]

  __shared__ float fw0s[L1R][P128];
  __shared__ float fw1s[L2R][P256];
  __shared__ float fw2s[L3R][P256];
  __shared__ float h1s[GB][P256];
  __shared__ float h2s[GB][P256];
  __shared__ float ysv[GB][P128];
  __shared__ float yloc[GB][NH];
  __shared__ float dxs[GB][NC];
  __shared__ float x0s[GB][NC];
  __shared__ float fb0s[L1R], fb1s[L2R], fb2s[L3R];
  __shared__ float tss[NSEQ];
  __shared__ float lgs[GB][NOUT], lses[GB];

  // ---- one-time: this slice's weights -> LDS ----
  {
    if (t < 256) {                       // fw0: 8 rows x 32 f4
      int row = t >> 5, j = t & 31;
      *(float4*)&fw0s[row][4*j] = *(const float4*)&fw0[(size_t)(s*L1R + row)*NH + 4*j];
    }
    {                                    // fw1: 8 rows x 64 f4 -> 1 f4/thread
      int r2 = t >> 6, j2 = t & 63;
      *(float4*)&fw1s[r2][4*j2] = *(const float4*)&fw1[(size_t)(s*L2R + r2)*NW + 4*j2];
    }
    #pragma unroll
    for (int i = 0; i < 8; ++i) {        // fw2: 64 rows x 64 f4 -> 8 f4/thread
      int e = t + BS*i; int r2 = e >> 6, j2 = e & 63;
      *(float4*)&fw2s[r2][4*j2] = *(const float4*)&fw2[(size_t)(s*L3R + r2)*NW + 4*j2];
    }
    if (t < L1R) fb0s[t] = fb0[s*L1R + t];
    if (t < L2R) fb1s[t] = fb1[s*L2R + t];
    if (t < L3R) fb2s[t] = fb2[s*L3R + t];
    if (t < NSEQ) tss[t] = ts[t];
  }

  // ---- init MLP (redundant per block, fully local) ----
  if (t < GB*NC) { int r = t >> 4, c = t & 15; x0s[r][c] = ca[((size_t)(gr0 + r)*NI)*NC + c]; }
  __syncthreads();
  #pragma unroll
  for (int i = 0; i < 4; ++i) {          // h1i: 2048 outs
    int e = t + BS*i; int r = e >> 8, row = e & 255;
    float a = ib0[row];
    #pragma unroll
    for (int k = 0; k < NC; ++k) a += iw0[row*NC + k] * x0s[r][k];
    h1s[r][row] = fmaxf(a, 0.f);
  }
  __syncthreads();
  #pragma unroll
  for (int i = 0; i < 4; ++i) {          // h2i
    int e = t + BS*i; int r = e >> 8, row = e & 255;
    float a = ib1[row];
    const float4* wr = (const float4*)&iw1[(size_t)row*NW];
    for (int k = 0; k < 64; ++k) a += dot4(wr[k], *(const float4*)&h1s[r][4*k]);
    h2s[r][row] = fmaxf(a, 0.f);
  }
  __syncthreads();
  #pragma unroll
  for (int i = 0; i < 2; ++i) {          // y0: 1024 outs
    int e = t + BS*i; int r = e >> 7, row = e & 127;
    float a = ib2[row];
    const float4* wr = (const float4*)&iw2[(size_t)row*NW];
    for (int k = 0; k < 64; ++k) a += dot4(wr[k], *(const float4*)&h2s[r][4*k]);
    yloc[r][row] = a;
  }
  __syncthreads();

  // ---- thread mappings ----
  const int lane = t & 63;
  const int w    = t >> 6;                      // wave index == batch row for L1/L2/L3
  const int yr   = t >> 5, yc4 = 4*(t & 31);    // t<256: one y-f4 (batch yr, cols yc4..+3)
  const int o    = t >> 3, q8 = t & 7;          // L1/L2: 8 threads per output
  const int orow = o & 7, obat = o >> 3;        // obat == w
  const int l3row = t & 63, l3c = t & 15, l3b = t >> 6;

  // ---- y and k stages live in registers (t<256) ----
  float4 yreg; f4v kreg[6];
  if (t < 256) yreg = *(const float4*)&yloc[yr][yc4];

  // ---- 62 Tsit5 substeps ----
  for (int ss = 0; ss < NSUB; ++ss) {
    const int iv = ss >> 1, jv = ss & 1;
    const float h = (tss[iv+1] - tss[iv]) * 0.5f;
    const float t0f = (float)jv * h;

    float cdv = 0.f, ccv = 0.f, cbv = 0.f;
    if (t >= 256 && t < 256 + GB*NC) {
      const int tc = t - 256;
      const size_t base = ((size_t)(gr0 + (tc >> 4))*NI + iv)*NC + (tc & 15);
      cdv = cd[base]; ccv = cc[base]; cbv = cb[base];
    }

    for (int st = 0; st < 6; ++st) {
      // ---- phase A: stage state from registers + dX/dt ----
      if (t < 256) {
        float4 v = yreg;
        for (int jj = 0; jj < st; ++jj) {
          const float a = h * ATAB[st][jj];
          v.x += a*kreg[jj][0]; v.y += a*kreg[jj][1];
          v.z += a*kreg[jj][2]; v.w += a*kreg[jj][3];
        }
        *(float4*)&ysv[yr][yc4] = v;
      } else if (t < 256 + GB*NC) {
        const int tc = t - 256;
        const float f = t0f + CNODE[st] * h;
        dxs[tc >> 4][tc & 15] = (3.f*cdv*f + 2.f*ccv)*f + cbv;
      }
      __syncthreads();

      // ---- L1: h1 slice -> packed coalesced store ([slice][batch][row]) ----
      {
        float a0 = 0.f, a1 = 0.f;
        #pragma unroll
        for (int i = 0; i < 4; i += 2) {
          a0 += dot4(*(const float4*)&fw0s[orow][4*(q8+8*i)],     *(const float4*)&ysv[obat][4*(q8+8*i)]);
          a1 += dot4(*(const float4*)&fw0s[orow][4*(q8+8*(i+1))], *(const float4*)&ysv[obat][4*(q8+8*(i+1))]);
        }
        float a = a0 + a1;
        a += __shfl_xor(a, 1); a += __shfl_xor(a, 2); a += __shfl_xor(a, 4);
        const float praw = __shfl(a, (lane & 7) * 8);   // lane L -> row (L&7) of batch w
        if (lane < 8)
          sta_f32(&h1cg[(s*GB + w)*L1R + lane], softplusf_(fb0s[lane] + praw));
      }
      group_barrier(slots, s, ++bseq);

      // consume full h1: one x4 agent load/thread, scatter to LDS
      {
        const f4v v = lda_f32x4(h1cg + 4*t);
        *(f4v*)&h1s[(t >> 1) & 7][(t >> 4)*8 + 4*(t & 1)] = v;
      }
      __syncthreads();

      // ---- L2: h2 slice -> packed coalesced store ----
      {
        float a0 = 0.f, a1 = 0.f;
        #pragma unroll
        for (int i = 0; i < 8; i += 2) {
          a0 += dot4(*(const float4*)&fw1s[orow][4*(q8+8*i)],     *(const float4*)&h1s[obat][4*(q8+8*i)]);
          a1 += dot4(*(const float4*)&fw1s[orow][4*(q8+8*(i+1))], *(const float4*)&h1s[obat][4*(q8+8*(i+1))]);
        }
        float a = a0 + a1;
        a += __shfl_xor(a, 1); a += __shfl_xor(a, 2); a += __shfl_xor(a, 4);
        const float praw = __shfl(a, (lane & 7) * 8);
        if (lane < 8)
          sta_f32(&h2cg[(s*GB + w)*L2R + lane], softplusf_(fb1s[lane] + praw));
      }
      group_barrier(slots, s, ++bseq);

      // consume full h2
      {
        const f4v v = lda_f32x4(h2cg + 4*t);
        *(f4v*)&h2s[(t >> 1) & 7][(t >> 4)*8 + 4*(t & 1)] = v;
      }
      __syncthreads();

      // ---- L3: one fw2 row per thread -> one x4 store per wave ----
      {
        const float4* wr = (const float4*)&fw2s[l3row][0];
        const float4* xr = (const float4*)&h2s[l3b][0];
        float a0 = 0.f, a1 = 0.f, a2 = 0.f, a3 = 0.f;
        #pragma unroll 4
        for (int i = 0; i < 64; i += 4) {
          a0 += dot4(wr[i+0], xr[i+0]);
          a1 += dot4(wr[i+1], xr[i+1]);
          a2 += dot4(wr[i+2], xr[i+2]);
          a3 += dot4(wr[i+3], xr[i+3]);
        }
        float v0 = tanhf(((a0+a1)+(a2+a3)) + fb2s[l3row]) * dxs[l3b][l3c];
        v0 += __shfl_xor(v0, 1);
        v0 += __shfl_xor(v0, 2);
        v0 += __shfl_xor(v0, 4);
        v0 += __shfl_xor(v0, 8);
        f4v pk;
        pk[0] = __shfl(v0, 0);  pk[1] = __shfl(v0, 16);
        pk[2] = __shfl(v0, 32); pk[3] = __shfl(v0, 48);
        if (lane == 0)
          sta_f32x4(&kvcg[((st*NSL + s)*GB + w)*4], pk);
      }
      group_barrier(slots, s, ++bseq);

      // consume this stage's k: one x4 per t<256 thread ([st][slice][batch][4])
      if (t < 256) {
        kreg[st] = lda_f32x4(kvcg + ((st*NSL + (t & 31))*GB + yr)*4);
      }
    }

    // ---- y update in registers ----
    if (t < 256) {
      #pragma unroll
      for (int s2 = 0; s2 < 6; ++s2) {
        const float a = h * BTAB[s2];
        yreg.x += a*kreg[s2][0]; yreg.y += a*kreg[s2][1];
        yreg.z += a*kreg[s2][2]; yreg.w += a*kreg[s2][3];
      }
    }
  }

  // ---- write y back for readout ----
  if (t < 256) *(float4*)&yloc[yr][yc4] = yreg;
  __syncthreads();

  // ---- readout by slice 0 of each group ----
  if (s == 0) {
    if (t < GB*NOUT) {
      const int r = t / NOUT, oo = t % NOUT;
      float a = lb[oo];
      const float4* wr = (const float4*)&lw[(size_t)oo*NH];
      #pragma unroll
      for (int k = 0; k < 32; ++k) a += dot4(wr[k], *(const float4*)&yloc[r][4*k]);
      lgs[r][oo] = a;
    }
    __syncthreads();
    if (t < GB) {
      float m = lgs[t][0];
      for (int oo = 1; oo < NOUT; ++oo) m = fmaxf(m, lgs[t][oo]);
      float se = 0.f;
      for (int oo = 0; oo < NOUT; ++oo) se += expf(lgs[t][oo] - m);
      lses[t] = m + logf(se);
    }
    __syncthreads();
    if (t < GB*NOUT) {
      const int r = t / NOUT, oo = t % NOUT;
      out[(gr0 + r)*NOUT + oo] = lgs[r][oo] - lses[r];
    }
  }
}

extern "C" void kernel_launch(void* const* d_in, const int* in_sizes, int n_in,
                              void* d_out, int out_size, void* d_ws, size_t ws_size,
                              hipStream_t stream) {
  const float* ts  = (const float*)d_in[0];
  const float* cd  = (const float*)d_in[1];
  const float* cc  = (const float*)d_in[2];
  const float* cb  = (const float*)d_in[3];
  const float* ca  = (const float*)d_in[4];
  const float* iw0 = (const float*)d_in[5];
  const float* ib0 = (const float*)d_in[6];
  const float* iw1 = (const float*)d_in[7];
  const float* ib1 = (const float*)d_in[8];
  const float* iw2 = (const float*)d_in[9];
  const float* ib2 = (const float*)d_in[10];
  const float* fw0 = (const float*)d_in[11];
  const float* fb0 = (const float*)d_in[12];
  const float* fw1 = (const float*)d_in[13];
  const float* fb1 = (const float*)d_in[14];
  const float* fw2 = (const float*)d_in[15];
  const float* fb2 = (const float*)d_in[16];
  const float* lw  = (const float*)d_in[17];
  const float* lb  = (const float*)d_in[18];

  char* ws = (char*)d_ws;
  unsigned* bar = (unsigned*)(ws + WS_BAR);
  float* h1c = (float*)(ws + WS_H1);
  float* h2c = (float*)(ws + WS_H2);
  float* kvc = (float*)(ws + WS_KV);

  bar_init<<<1, 512, 0, stream>>>(bar);
  ncde_fwd<<<NBLK, BS, 0, stream>>>(ts, cd, cc, cb, ca, iw0, ib0, iw1, ib1, iw2, ib2,
                                    fw0, fb0, fw1, fb1, fw2, fb2, lw, lb,
                                    bar, h1c, h2c, kvc, (float*)d_out);
}